// Round 2
// baseline (175.570 us; speedup 1.0000x reference)
//
#include <hip/hip_runtime.h>
#include <stdint.h>

// OctonionLinear == GEMM: out[b, i*8+k] = sum_{j,p} x[b, j*8+p] * W[i,j,p,k] + bias[i,k]
// M=512 (batch), N=4096 (out_oct*8), K=4096 (in_oct*8), fp32 in/out, bf16 MFMA.
// R2 changes vs R1 (154.7 us total; prep ~95 us, gemm ~59.5 us):
//  - prep transpose now stages the 8x8 p<->k block transpose through LDS so
//    global writes are 512B-contiguous runs (R1 wrote 16B at 8KB stride).
//  - GEMM KSPLIT 4->8: 1024 blocks = 4 blocks/CU = 16 waves/CU (VGPR=92 caps
//    at 16 waves; LDS 16KB x 4 = 64KB of 160KB). R1 was latency-bound at
//    Occupancy 17.8%, MfmaUtil 10.5%.

#define M_DIM 512
#define N_DIM 4096
#define K_DIM 4096
#define KSPLIT 8

typedef __bf16 bf16x8 __attribute__((ext_vector_type(8)));
typedef float f32x4 __attribute__((ext_vector_type(4)));

__device__ inline unsigned short f2bf(float f) {
  union { float f; unsigned int u; } v;
  v.f = f;
  unsigned int u = v.u;
  // round-to-nearest-even bf16
  unsigned int r = (u + 0x7fffu + ((u >> 16) & 1u)) >> 16;
  return (unsigned short)r;
}

// blocks [0,8192): weight transpose+convert -> bt[nn][kk], LDS-staged.
//   block = (i, jg): i in [0,512), jg in [0,16) covering 32 j each.
// blocks [8192,9216): x convert -> abf (row-major bf16), 8 el/thread.
// blocks [9216,11264): out = bias broadcast, 4 el/thread.
__global__ __launch_bounds__(256) void prep_kernel(
    const float* __restrict__ x, const float* __restrict__ w,
    const float* __restrict__ bias, unsigned short* __restrict__ abf,
    unsigned short* __restrict__ bt, float* __restrict__ out) {
  const int bid = blockIdx.x;
  const int tid = threadIdx.x;
  if (bid < 8192) {
    __shared__ __align__(16) unsigned short l[8][256];  // [k][jj*8+p], 4KB
    const int i = bid >> 4;
    const int jg = bid & 15;
    const int k = tid & 7;
    const int jj = tid >> 3;  // 0..31
    // read w[i][jg*32+jj][p][k] for p=0..7 (stride-8 floats; lines fully
    // consumed across the p loop via L1/L2, so no over-fetch)
    const float* wb = w + ((size_t)(i * 512 + jg * 32 + jj) * 64 + k);
    __attribute__((aligned(16))) unsigned short o[8];
#pragma unroll
    for (int p = 0; p < 8; ++p) o[p] = f2bf(wb[p * 8]);
    *(uint4*)&l[k][jj * 8] = *(const uint4*)o;
    __syncthreads();
    // write out 8 rows x 512B contiguous: row r = nn=i*8+r, cols jg*256..+256
    const int r = tid >> 5, c = tid & 31;
    *(uint4*)(bt + (size_t)(i * 8 + r) * K_DIM + jg * 256 + c * 8) =
        *(const uint4*)&l[r][c * 8];
  } else if (bid < 9216) {
    int g = (bid - 8192) * 256 + tid;  // [0, 262144); 8 elements each
    const float4* xi = (const float4*)x;
    float4 a = xi[g * 2];
    float4 b = xi[g * 2 + 1];
    __attribute__((aligned(16))) unsigned short o[8] = {
        f2bf(a.x), f2bf(a.y), f2bf(a.z), f2bf(a.w),
        f2bf(b.x), f2bf(b.y), f2bf(b.z), f2bf(b.w)};
    *(uint4*)(abf + (size_t)g * 8) = *(const uint4*)o;
  } else {
    int g = (bid - 9216) * 256 + tid;  // [0, 524288); 4 elements each
    int el = g * 4;
    int col = el & (N_DIM - 1);
    *(float4*)(out + el) = *(const float4*)(bias + col);
  }
}

__device__ inline void gld16(const void* g, void* l) {
  __builtin_amdgcn_global_load_lds(
      (const __attribute__((address_space(1))) unsigned int*)g,
      (__attribute__((address_space(3))) unsigned int*)l, 16, 0, 0);
}

__global__ __launch_bounds__(256) void gemm_kernel(
    const unsigned short* __restrict__ A, const unsigned short* __restrict__ Bt,
    float* __restrict__ out) {
  __shared__ __align__(16) unsigned short lA[128 * 32];  // [m][k] 8 KB
  __shared__ __align__(16) unsigned short lB[128 * 32];  // [n][k] 8 KB
  const int t = threadIdx.x;
  const int n0 = blockIdx.x * 128;
  const int m0 = blockIdx.y * 128;
  const int kc0 = blockIdx.z * (K_DIM / KSPLIT);
  const int w = t >> 6;
  const int lane = t & 63;
  const int wr = w >> 1;     // wave row (0..1) -> 64 rows of M
  const int wc = w & 1;      // wave col (0..1) -> 64 cols of N
  const int lrow = lane & 15;
  const int kb = lane >> 4;  // k-block 0..3 (8 bf16 each)

  f32x4 acc[4][4] = {};

  // staging: 512 x 16B per tile; thread issues segments t and t+256.
  // LDS dest = wave-uniform base + lane*16 (contiguous), matching [row][k].
  const int s0 = t, s1 = t + 256;
  const int row0 = s0 >> 2, c0 = (s0 & 3) * 8;
  const int row1 = s1 >> 2, c1 = (s1 & 3) * 8;

  for (int it = 0; it < (K_DIM / KSPLIT) / 32; ++it) {
    const int kk = kc0 + it * 32;
    __syncthreads();  // prior iter's ds_reads done before LDS overwrite
    gld16(A + (size_t)(m0 + row0) * K_DIM + kk + c0, (char*)lA + s0 * 16);
    gld16(Bt + (size_t)(n0 + row0) * K_DIM + kk + c0, (char*)lB + s0 * 16);
    gld16(A + (size_t)(m0 + row1) * K_DIM + kk + c1, (char*)lA + s1 * 16);
    gld16(Bt + (size_t)(n0 + row1) * K_DIM + kk + c1, (char*)lB + s1 * 16);
    __syncthreads();  // compiler drains vmcnt(0) before s_barrier

    bf16x8 af[4], bfr[4];
#pragma unroll
    for (int mt = 0; mt < 4; ++mt)
      af[mt] = *(const bf16x8*)(lA + (wr * 64 + mt * 16 + lrow) * 32 + kb * 8);
#pragma unroll
    for (int nt = 0; nt < 4; ++nt)
      bfr[nt] = *(const bf16x8*)(lB + (wc * 64 + nt * 16 + lrow) * 32 + kb * 8);
#pragma unroll
    for (int mt = 0; mt < 4; ++mt)
#pragma unroll
      for (int nt = 0; nt < 4; ++nt)
        acc[mt][nt] = __builtin_amdgcn_mfma_f32_16x16x32_bf16(
            af[mt], bfr[nt], acc[mt][nt], 0, 0, 0);
  }

  // C/D layout (verified m89/m91): col = lane&15, row = (lane>>4)*4 + reg
#pragma unroll
  for (int mt = 0; mt < 4; ++mt) {
    const int gmb = m0 + wr * 64 + mt * 16 + kb * 4;
#pragma unroll
    for (int nt = 0; nt < 4; ++nt) {
      const int gn = n0 + wc * 64 + nt * 16 + lrow;
#pragma unroll
      for (int r = 0; r < 4; ++r)
        atomicAdd(out + (size_t)(gmb + r) * N_DIM + gn, acc[mt][nt][r]);
    }
  }
}

extern "C" void kernel_launch(void* const* d_in, const int* in_sizes, int n_in,
                              void* d_out, int out_size, void* d_ws,
                              size_t ws_size, hipStream_t stream) {
  const float* x = (const float*)d_in[0];     // [512, 4096]
  const float* w = (const float*)d_in[1];     // [512, 512, 8, 8]
  const float* bias = (const float*)d_in[2];  // [512, 8]
  float* out = (float*)d_out;                 // [512, 4096]

  unsigned short* abf = (unsigned short*)d_ws;       // 4 MB bf16 A
  unsigned short* bt = abf + (size_t)M_DIM * K_DIM;  // 32 MB bf16 B^T

  prep_kernel<<<11264, 256, 0, stream>>>(x, w, bias, abf, bt, out);

  dim3 grid(N_DIM / 128, M_DIM / 128, KSPLIT);  // 32 x 4 x 8 = 1024 blocks
  gemm_kernel<<<grid, 256, 0, stream>>>(abf, bt, out);
}

// Round 3
// 155.690 us; speedup vs baseline: 1.1277x; 1.1277x over previous
//
#include <hip/hip_runtime.h>
#include <stdint.h>

// OctonionLinear == GEMM: out[b, i*8+k] = sum_{j,p} x[b, j*8+p] * W[i,j,p,k] + bias[i,k]
// M=512, N=4096, K=4096, fp32 in/out, bf16 MFMA.
// R3: (a) prep W-transpose now reads W in contiguous 16KB chunks (fully
//     coalesced float4) and transposes via LDS (R1/R2 read stride-8 dwords —
//     that, not the writes, was prep's bottleneck).
//     (b) GEMM K-loop is single-barrier double-buffered: prefetch tile it+1
//     via global_load_lds into the ping-pong LDS half right after the
//     barrier, then compute tile it. The vmcnt(0) drain at the next barrier
//     lands a full compute phase after issue -> HBM latency mostly hidden.
//     (c) KSPLIT back to 4 (R2 showed KSPLIT8's extra atomics cost ~16us).

#define M_DIM 512
#define N_DIM 4096
#define K_DIM 4096
#define KSPLIT 4

typedef __bf16 bf16x8 __attribute__((ext_vector_type(8)));
typedef float f32x4 __attribute__((ext_vector_type(4)));

__device__ inline unsigned short f2bf(float f) {
  union { float f; unsigned int u; } v;
  v.f = f;
  unsigned int u = v.u;
  unsigned int r = (u + 0x7fffu + ((u >> 16) & 1u)) >> 16;  // RNE
  return (unsigned short)r;
}

// blocks [0,4096): W transpose+convert -> bt[nn][kk]. Block = (i, jg):
//   i in [0,512), jg in [0,8); chunk = W[i][jg*64 .. jg*64+64][*][*] (16KB,
//   read contiguously). Thread t reads floats [t*16, t*16+16) of the chunk:
//   j' = t>>2 fixed, p in {2(t&3), 2(t&3)+1}, k = 0..7 -> packs (p,p+1) pairs
//   per k into b32 LDS writes of lT[k][j'*8+p]; then 8 rows written out in
//   1KB contiguous runs.
// blocks [4096,5120): x convert -> abf, 8 el/thread.
// blocks [5120,7168): out = bias broadcast, 4 el/thread.
__global__ __launch_bounds__(256) void prep_kernel(
    const float* __restrict__ x, const float* __restrict__ w,
    const float* __restrict__ bias, unsigned short* __restrict__ abf,
    unsigned short* __restrict__ bt, float* __restrict__ out) {
  const int bid = blockIdx.x;
  const int t = threadIdx.x;
  if (bid < 4096) {
    __shared__ __align__(16) unsigned short lT[8][512];  // [k][j'*8+p], 8KB
    const int i = bid >> 3;
    const int jg = bid & 7;
    const float4* src =
        (const float4*)(w + (size_t)i * 32768 + jg * 4096 + t * 16);
    float4 v0 = src[0], v1 = src[1], v2 = src[2], v3 = src[3];
    const int jp = (t >> 2) * 8 + (t & 3) * 2;  // j'*8 + p0 (even)
    unsigned int* dst32;
    const float* lo = (const float*)&v0;  // k=0..3, p0   (v1: k=4..7)
    const float* hi = (const float*)&v2;  // k=0..3, p0+1 (v3: k=4..7)
#pragma unroll
    for (int k = 0; k < 4; ++k) {
      unsigned int pk =
          (unsigned int)f2bf(lo[k]) | ((unsigned int)f2bf(hi[k]) << 16);
      *(unsigned int*)&lT[k][jp] = pk;
    }
    lo = (const float*)&v1;
    hi = (const float*)&v3;
#pragma unroll
    for (int k = 0; k < 4; ++k) {
      unsigned int pk =
          (unsigned int)f2bf(lo[k]) | ((unsigned int)f2bf(hi[k]) << 16);
      *(unsigned int*)&lT[k + 4][jp] = pk;
    }
    __syncthreads();
    // write rows: r = t>>5 (0..7), c = t&31: 32B per thread, 1KB runs
    const int r = t >> 5, c = t & 31;
    const uint4* s = (const uint4*)&lT[r][c * 16];
    uint4* d = (uint4*)(bt + (size_t)(i * 8 + r) * K_DIM + jg * 512 + c * 16);
    d[0] = s[0];
    d[1] = s[1];
  } else if (bid < 5120) {
    int g = (bid - 4096) * 256 + t;  // [0, 262144); 8 elements each
    const float4* xi = (const float4*)x;
    float4 a = xi[g * 2];
    float4 b = xi[g * 2 + 1];
    __attribute__((aligned(16))) unsigned short o[8] = {
        f2bf(a.x), f2bf(a.y), f2bf(a.z), f2bf(a.w),
        f2bf(b.x), f2bf(b.y), f2bf(b.z), f2bf(b.w)};
    *(uint4*)(abf + (size_t)g * 8) = *(const uint4*)o;
  } else {
    int g = (bid - 5120) * 256 + t;  // [0, 524288); 4 elements each
    int el = g * 4;
    int col = el & (N_DIM - 1);
    *(float4*)(out + el) = *(const float4*)(bias + col);
  }
}

__device__ inline void gld16(const void* g, void* l) {
  __builtin_amdgcn_global_load_lds(
      (const __attribute__((address_space(1))) unsigned int*)g,
      (__attribute__((address_space(3))) unsigned int*)l, 16, 0, 0);
}

__global__ __launch_bounds__(256) void gemm_kernel(
    const unsigned short* __restrict__ A, const unsigned short* __restrict__ Bt,
    float* __restrict__ out) {
  __shared__ __align__(16) unsigned short lA[2][128 * 32];  // ping-pong, 16KB
  __shared__ __align__(16) unsigned short lB[2][128 * 32];  // ping-pong, 16KB
  const int t = threadIdx.x;
  const int n0 = blockIdx.x * 128;
  const int m0 = blockIdx.y * 128;
  const int kc0 = blockIdx.z * (K_DIM / KSPLIT);
  const int w = t >> 6;
  const int lane = t & 63;
  const int wr = w >> 1;     // wave row -> 64 rows of M
  const int wc = w & 1;      // wave col -> 64 cols of N
  const int lrow = lane & 15;
  const int kb = lane >> 4;  // k-block 0..3 (8 bf16 each)

  f32x4 acc[4][4] = {};

  // staging: 512 x 16B per tile per matrix; thread issues segments t, t+256.
  const int s0 = t, s1 = t + 256;
  const int row0 = s0 >> 2, c0 = (s0 & 3) * 8;
  const int row1 = s1 >> 2, c1 = (s1 & 3) * 8;
  const size_t aO0 = (size_t)(m0 + row0) * K_DIM + c0;
  const size_t aO1 = (size_t)(m0 + row1) * K_DIM + c1;
  const size_t bO0 = (size_t)(n0 + row0) * K_DIM + c0;
  const size_t bO1 = (size_t)(n0 + row1) * K_DIM + c1;

  const int NIT = (K_DIM / KSPLIT) / 32;  // 32

  // preload tile 0 into buffer 0
  gld16(A + aO0 + kc0, (char*)lA[0] + s0 * 16);
  gld16(Bt + bO0 + kc0, (char*)lB[0] + s0 * 16);
  gld16(A + aO1 + kc0, (char*)lA[0] + (s1 - 256) * 16 + 4096);
  gld16(Bt + bO1 + kc0, (char*)lB[0] + (s1 - 256) * 16 + 4096);

  for (int it = 0; it < NIT; ++it) {
    // Barrier: (1) drains vmcnt for the prefetch issued last iter (it had a
    // full compute phase in flight), (2) protects the buffer being refilled
    // (all waves' ds_reads of it-1 complete).
    __syncthreads();
    if (it + 1 < NIT) {
      const int kk = kc0 + (it + 1) * 32;
      char* dA = (char*)lA[(it + 1) & 1];
      char* dB = (char*)lB[(it + 1) & 1];
      gld16(A + aO0 + kk, dA + s0 * 16);
      gld16(Bt + bO0 + kk, dB + s0 * 16);
      gld16(A + aO1 + kk, dA + (s1 - 256) * 16 + 4096);
      gld16(Bt + bO1 + kk, dB + (s1 - 256) * 16 + 4096);
    }
    const unsigned short* cA = lA[it & 1];
    const unsigned short* cB = lB[it & 1];

    bf16x8 af[4], bfr[4];
#pragma unroll
    for (int mt = 0; mt < 4; ++mt)
      af[mt] = *(const bf16x8*)(cA + (wr * 64 + mt * 16 + lrow) * 32 + kb * 8);
#pragma unroll
    for (int nt = 0; nt < 4; ++nt)
      bfr[nt] = *(const bf16x8*)(cB + (wc * 64 + nt * 16 + lrow) * 32 + kb * 8);
#pragma unroll
    for (int mt = 0; mt < 4; ++mt)
#pragma unroll
      for (int nt = 0; nt < 4; ++nt)
        acc[mt][nt] = __builtin_amdgcn_mfma_f32_16x16x32_bf16(
            af[mt], bfr[nt], acc[mt][nt], 0, 0, 0);
  }

  // C/D layout (verified m89/m91): col = lane&15, row = (lane>>4)*4 + reg
#pragma unroll
  for (int mt = 0; mt < 4; ++mt) {
    const int gmb = m0 + wr * 64 + mt * 16 + kb * 4;
#pragma unroll
    for (int nt = 0; nt < 4; ++nt) {
      const int gn = n0 + wc * 64 + nt * 16 + lrow;
#pragma unroll
      for (int r = 0; r < 4; ++r)
        atomicAdd(out + (size_t)(gmb + r) * N_DIM + gn, acc[mt][nt][r]);
    }
  }
}

extern "C" void kernel_launch(void* const* d_in, const int* in_sizes, int n_in,
                              void* d_out, int out_size, void* d_ws,
                              size_t ws_size, hipStream_t stream) {
  const float* x = (const float*)d_in[0];     // [512, 4096]
  const float* w = (const float*)d_in[1];     // [512, 512, 8, 8]
  const float* bias = (const float*)d_in[2];  // [512, 8]
  float* out = (float*)d_out;                 // [512, 4096]

  unsigned short* abf = (unsigned short*)d_ws;       // 4 MB bf16 A
  unsigned short* bt = abf + (size_t)M_DIM * K_DIM;  // 32 MB bf16 B^T

  prep_kernel<<<7168, 256, 0, stream>>>(x, w, bias, abf, bt, out);

  dim3 grid(N_DIM / 128, M_DIM / 128, KSPLIT);  // 32 x 4 x 4 = 512 blocks
  gemm_kernel<<<grid, 256, 0, stream>>>(abf, bt, out);
}

// Round 4
// 155.614 us; speedup vs baseline: 1.1282x; 1.0005x over previous
//
#include <hip/hip_runtime.h>
#include <stdint.h>

// OctonionLinear == GEMM: out[b, i*8+k] = sum_{j,p} x[b, j*8+p] * W[i,j,p,k] + bias[i,k]
// M=512, N=4096, K=4096, fp32 in/out, bf16 MFMA.
// R4: barrier-free per-wave pipelined K-loop. Each wave owns a private
//   2x8KB LDS ping-pong (A 4KB + B 4KB per buffer) and stages its own
//   64-row slabs via 8x global_load_lds per iter. NO __syncthreads in the
//   loop: per-wave s_waitcnt lgkmcnt(0) before overwriting a buffer, and
//   vmcnt(8) (never 0) to consume the ready buffer while the next 8 loads
//   remain in flight — the AITER-style structure the 2-barrier m97 loop
//   can't express (R3's barrier drained vmcnt(0) every iter -> 2070 cyc per
//   block-iter vs ~600 of real work; MfmaUtil stuck at 11.5%).
//   LDS 64KB/block -> 2 blocks/CU (8 independent waves/CU hide L2 latency).
// prep unchanged from R3; KSPLIT=4 + atomic epilogue unchanged.

#define M_DIM 512
#define N_DIM 4096
#define K_DIM 4096
#define KSPLIT 4
#define NIT ((K_DIM / KSPLIT) / 32)  // 32

typedef __bf16 bf16x8 __attribute__((ext_vector_type(8)));
typedef float f32x4 __attribute__((ext_vector_type(4)));

__device__ inline unsigned short f2bf(float f) {
  union { float f; unsigned int u; } v;
  v.f = f;
  unsigned int u = v.u;
  unsigned int r = (u + 0x7fffu + ((u >> 16) & 1u)) >> 16;  // RNE
  return (unsigned short)r;
}

// blocks [0,4096): W transpose+convert -> bt[nn][kk], coalesced 16KB chunks.
// blocks [4096,5120): x convert -> abf, 8 el/thread.
// blocks [5120,7168): out = bias broadcast, 4 el/thread.
__global__ __launch_bounds__(256) void prep_kernel(
    const float* __restrict__ x, const float* __restrict__ w,
    const float* __restrict__ bias, unsigned short* __restrict__ abf,
    unsigned short* __restrict__ bt, float* __restrict__ out) {
  const int bid = blockIdx.x;
  const int t = threadIdx.x;
  if (bid < 4096) {
    __shared__ __align__(16) unsigned short lT[8][512];  // [k][j'*8+p], 8KB
    const int i = bid >> 3;
    const int jg = bid & 7;
    const float4* src =
        (const float4*)(w + (size_t)i * 32768 + jg * 4096 + t * 16);
    float4 v0 = src[0], v1 = src[1], v2 = src[2], v3 = src[3];
    const int jp = (t >> 2) * 8 + (t & 3) * 2;  // j'*8 + p0 (even)
    const float* lo = (const float*)&v0;  // k=0..3, p0   (v1: k=4..7)
    const float* hi = (const float*)&v2;  // k=0..3, p0+1 (v3: k=4..7)
#pragma unroll
    for (int k = 0; k < 4; ++k) {
      unsigned int pk =
          (unsigned int)f2bf(lo[k]) | ((unsigned int)f2bf(hi[k]) << 16);
      *(unsigned int*)&lT[k][jp] = pk;
    }
    lo = (const float*)&v1;
    hi = (const float*)&v3;
#pragma unroll
    for (int k = 0; k < 4; ++k) {
      unsigned int pk =
          (unsigned int)f2bf(lo[k]) | ((unsigned int)f2bf(hi[k]) << 16);
      *(unsigned int*)&lT[k + 4][jp] = pk;
    }
    __syncthreads();
    const int r = t >> 5, c = t & 31;  // 32B/thread, 1KB contiguous runs
    const uint4* s = (const uint4*)&lT[r][c * 16];
    uint4* d = (uint4*)(bt + (size_t)(i * 8 + r) * K_DIM + jg * 512 + c * 16);
    d[0] = s[0];
    d[1] = s[1];
  } else if (bid < 5120) {
    int g = (bid - 4096) * 256 + t;  // [0, 262144); 8 elements each
    const float4* xi = (const float4*)x;
    float4 a = xi[g * 2];
    float4 b = xi[g * 2 + 1];
    __attribute__((aligned(16))) unsigned short o[8] = {
        f2bf(a.x), f2bf(a.y), f2bf(a.z), f2bf(a.w),
        f2bf(b.x), f2bf(b.y), f2bf(b.z), f2bf(b.w)};
    *(uint4*)(abf + (size_t)g * 8) = *(const uint4*)o;
  } else {
    int g = (bid - 5120) * 256 + t;  // [0, 524288); 4 elements each
    int el = g * 4;
    int col = el & (N_DIM - 1);
    *(float4*)(out + el) = *(const float4*)(bias + col);
  }
}

__device__ inline void gld16(const void* g, void* l) {
  __builtin_amdgcn_global_load_lds(
      (const __attribute__((address_space(1))) unsigned int*)g,
      (__attribute__((address_space(3))) unsigned int*)l, 16, 0, 0);
}

// s_waitcnt immediates (gfx9 encoding: vmcnt[3:0]=bits3:0, expcnt=6:4,
// lgkmcnt=11:8, vmcnt[5:4]=15:14). "Ignore" = field at max.
#define WAIT_VM8 0x0F78   // vmcnt(8), lgkm/exp ignored
#define WAIT_VM0 0x0F70   // vmcnt(0), lgkm/exp ignored
#define WAIT_LGKM0 0xC07F // lgkmcnt(0), vmcnt/exp ignored

__global__ __launch_bounds__(256) void gemm_kernel(
    const unsigned short* __restrict__ A, const unsigned short* __restrict__ Bt,
    float* __restrict__ out) {
  // per-wave private: [wave][buf][A 4KB | B 4KB]
  __shared__ __align__(16) char lds[4 * 2 * 8192];  // 64KB
  const int t = threadIdx.x;
  const int n0 = blockIdx.x * 128;
  const int m0 = blockIdx.y * 128;
  const int kc0 = blockIdx.z * (K_DIM / KSPLIT);
  const int w = t >> 6;
  const int lane = t & 63;
  const int wr = w >> 1;     // wave row -> 64 rows of M
  const int wc = w & 1;      // wave col -> 64 cols of N
  const int lrow = lane & 15;
  const int kb = lane >> 4;  // k-block 0..3 (8 bf16 each)
  char* wbase = lds + w * 16384;
  char* ldsLane = wbase + lane * 16;  // linear-in-lane (HW: base + lane*16)

  // staging global base: instr q covers rows q*16+(lane>>2), k-chunk (lane&3)
  const int srow = lane >> 2;
  const int scol = (lane & 3) * 8;
  const unsigned short* gA0 =
      A + (size_t)(m0 + wr * 64 + srow) * K_DIM + kc0 + scol;
  const unsigned short* gB0 =
      Bt + (size_t)(n0 + wc * 64 + srow) * K_DIM + kc0 + scol;

  f32x4 acc[4][4] = {};

  auto issue = [&](int it) {
    char* dA = ldsLane + (it & 1) * 8192;
    char* dB = dA + 4096;
    const unsigned short* gA = gA0 + it * 32;
    const unsigned short* gB = gB0 + it * 32;
#pragma unroll
    for (int q = 0; q < 4; ++q) {
      gld16(gA + (size_t)q * 16 * K_DIM, dA + q * 1024);
      gld16(gB + (size_t)q * 16 * K_DIM, dB + q * 1024);
    }
  };

  issue(0);  // 8 loads in flight
  for (int it = 0; it < NIT; ++it) {
    if (it + 1 < NIT) {
      // my own ds_reads of the buffer being refilled finished last iter;
      // wave-local wait, no barrier.
      __builtin_amdgcn_s_waitcnt(WAIT_LGKM0);
      issue(it + 1);                           // 16 in flight
      __builtin_amdgcn_s_waitcnt(WAIT_VM8);    // oldest 8 (current buf) done
    } else {
      __builtin_amdgcn_s_waitcnt(WAIT_VM0);
    }
    const unsigned short* cA = (const unsigned short*)(wbase + (it & 1) * 8192);
    const unsigned short* cB = cA + 2048;  // +4KB

    bf16x8 af[4], bfr[4];
#pragma unroll
    for (int mt = 0; mt < 4; ++mt)
      af[mt] = *(const bf16x8*)(cA + (mt * 16 + lrow) * 32 + kb * 8);
#pragma unroll
    for (int nt = 0; nt < 4; ++nt)
      bfr[nt] = *(const bf16x8*)(cB + (nt * 16 + lrow) * 32 + kb * 8);
#pragma unroll
    for (int mt = 0; mt < 4; ++mt)
#pragma unroll
      for (int nt = 0; nt < 4; ++nt)
        acc[mt][nt] = __builtin_amdgcn_mfma_f32_16x16x32_bf16(
            af[mt], bfr[nt], acc[mt][nt], 0, 0, 0);
  }

  // C/D layout (verified m89/m91): col = lane&15, row = (lane>>4)*4 + reg
#pragma unroll
  for (int mt = 0; mt < 4; ++mt) {
    const int gmb = m0 + wr * 64 + mt * 16 + kb * 4;
#pragma unroll
    for (int nt = 0; nt < 4; ++nt) {
      const int gn = n0 + wc * 64 + nt * 16 + lrow;
#pragma unroll
      for (int r = 0; r < 4; ++r)
        atomicAdd(out + (size_t)(gmb + r) * N_DIM + gn, acc[mt][nt][r]);
    }
  }
}

extern "C" void kernel_launch(void* const* d_in, const int* in_sizes, int n_in,
                              void* d_out, int out_size, void* d_ws,
                              size_t ws_size, hipStream_t stream) {
  const float* x = (const float*)d_in[0];     // [512, 4096]
  const float* w = (const float*)d_in[1];     // [512, 512, 8, 8]
  const float* bias = (const float*)d_in[2];  // [512, 8]
  float* out = (float*)d_out;                 // [512, 4096]

  unsigned short* abf = (unsigned short*)d_ws;       // 4 MB bf16 A
  unsigned short* bt = abf + (size_t)M_DIM * K_DIM;  // 32 MB bf16 B^T

  prep_kernel<<<7168, 256, 0, stream>>>(x, w, bias, abf, bt, out);

  dim3 grid(N_DIM / 128, M_DIM / 128, KSPLIT);  // 32 x 4 x 4 = 512 blocks
  gemm_kernel<<<grid, 256, 0, stream>>>(abf, bt, out);
}